// Round 8
// baseline (387.159 us; speedup 1.0000x reference)
//
#include <hip/hip_runtime.h>
#include <hip/hip_bf16.h>
#include <math.h>

// Problem constants (B=4, L=2048 -> N=8192 tokens)
#define NTOK 8192
#define DDIM 512
#define HDIM 1024
#define NEXP 8
#define TOPK 2
#define TOTSLOT (NTOK * TOPK)    // 16384 token-expert slots
#define NBLK_GATE (NTOK / 4)     // 2048 gate blocks (4 tokens each)
#define RBMAX 144                // >= max Sum_e ceil(cnt_e/128) = 135

typedef __bf16 bf16;
typedef __attribute__((ext_vector_type(8))) __bf16 bf16x8;
typedef __attribute__((ext_vector_type(4))) float f32x4;

// ---------------- workspace layout (bytes), total 67,383,296 ----------------
#define WS_CUMOFF_OFF     2048                    // int[9]
#define WS_RBE_OFF        2112                    // int[144]
#define WS_RBR_OFF        2688                    // int[144]
#define WS_PSUM_PART_OFF  4096                    // [2048][8] f32
#define WS_ZL_PART_OFF    69632                   // [2048] f32
#define WS_GATES_OFF      77824                   // [16384] f32
#define WS_LIST_OFF       143360                  // ushort[8][8192]
#define WS_XG_OFF         274432                  // bf16[16384][512]
#define WS_W1T_OFF        17051648                // bf16[E][H][D]
#define WS_W2T_OFF        25440256                // bf16[E][D][H]
#define WS_HB_OFF         33828864                // bf16[16384][1024]

#define GL2LDS(g, l) __builtin_amdgcn_global_load_lds( \
    (const __attribute__((address_space(1))) void*)(g), \
    (__attribute__((address_space(3))) void*)(l), 16, 0, 0)

// ---------------------------------------------------------------------------
// Gating (unchanged, passing).
// ---------------------------------------------------------------------------
__global__ __launch_bounds__(256)
void gate_kernel(const float* __restrict__ x, const float* __restrict__ wg,
                 int* __restrict__ counts, float* __restrict__ psum_part,
                 float* __restrict__ zl_part, float* __restrict__ gates,
                 unsigned short* __restrict__ list) {
    __shared__ float wls[NEXP * DDIM];
    __shared__ float blk_psum[NEXP];
    __shared__ float blk_zl;
    const int t = threadIdx.x;

    for (int i = t; i < NEXP * DDIM / 4; i += 256)
        ((float4*)wls)[i] = ((const float4*)wg)[i];
    if (t < NEXP) blk_psum[t] = 0.f;
    if (t == 0) blk_zl = 0.f;
    __syncthreads();

    const int wave = t >> 6, lane = t & 63;
    const int n = blockIdx.x * 4 + wave;
    const float* xr = x + (size_t)n * DDIM;

    float acc[NEXP];
#pragma unroll
    for (int e = 0; e < NEXP; ++e) acc[e] = 0.f;
#pragma unroll
    for (int it = 0; it < DDIM / 64; ++it) {
        const float xv = xr[lane + 64 * it];
#pragma unroll
        for (int e = 0; e < NEXP; ++e)
            acc[e] = fmaf(xv, wls[e * DDIM + lane + 64 * it], acc[e]);
    }
#pragma unroll
    for (int e = 0; e < NEXP; ++e) {
#pragma unroll
        for (int off = 32; off > 0; off >>= 1)
            acc[e] += __shfl_xor(acc[e], off);
    }

    float m = acc[0];
#pragma unroll
    for (int e = 1; e < NEXP; ++e) m = fmaxf(m, acc[e]);
    float p[NEXP];
    float se = 0.f;
#pragma unroll
    for (int e = 0; e < NEXP; ++e) { p[e] = expf(acc[e] - m); se += p[e]; }
    const float lse = m + logf(se);
    const float inv = 1.f / se;
#pragma unroll
    for (int e = 0; e < NEXP; ++e) p[e] *= inv;

    int e0 = 0; float g0 = p[0];
#pragma unroll
    for (int e = 1; e < NEXP; ++e) if (p[e] > g0) { g0 = p[e]; e0 = e; }
    int e1 = -1; float g1 = -1.f;
#pragma unroll
    for (int e = 0; e < NEXP; ++e) if (e != e0 && p[e] > g1) { g1 = p[e]; e1 = e; }
    const float denom = g0 + g1 + 1e-6f;

    if (lane == 0) {
        gates[n * 2 + 0] = g0 / denom;
        gates[n * 2 + 1] = g1 / denom;
        const int p0 = atomicAdd(&counts[e0 * 64], 1);
        list[e0 * NTOK + p0] = (unsigned short)(n * 2 + 0);
        const int p1 = atomicAdd(&counts[e1 * 64], 1);
        list[e1 * NTOK + p1] = (unsigned short)(n * 2 + 1);
#pragma unroll
        for (int e = 0; e < NEXP; ++e) atomicAdd(&blk_psum[e], p[e]);
        atomicAdd(&blk_zl, lse * lse);
    }
    __syncthreads();
    if (t < NEXP) psum_part[blockIdx.x * NEXP + t] = blk_psum[t];
    if (t == 0) zl_part[blockIdx.x] = blk_zl;
}

// ---------------------------------------------------------------------------
__global__ void plan_kernel(const int* __restrict__ counts, int* __restrict__ cumoff,
                            int* __restrict__ rb_e, int* __restrict__ rb_r) {
    if (threadIdx.x == 0 && blockIdx.x == 0) {
        int off = 0, idx = 0;
        for (int e = 0; e < NEXP; ++e) {
            cumoff[e] = off;
            const int c = counts[e * 64];
            off += c;
            for (int r = 0; r < c; r += 128) { rb_e[idx] = e; rb_r[idx] = r; ++idx; }
        }
        cumoff[NEXP] = off;
        for (; idx < RBMAX; ++idx) { rb_e[idx] = -1; rb_r[idx] = 0; }
    }
}

// ---------------------------------------------------------------------------
__global__ __launch_bounds__(256)
void pack_kernel(const float* __restrict__ x, const unsigned short* __restrict__ list,
                 const int* __restrict__ cumoff, bf16* __restrict__ xg) {
    const int wave = threadIdx.x >> 6, lane = threadIdx.x & 63;
    const int slot = blockIdx.x * 4 + wave;
    int e = 0;
#pragma unroll
    for (int k = 1; k < NEXP; ++k) e += (slot >= cumoff[k]) ? 1 : 0;
    const int pos = slot - cumoff[e];
    const int entry = list[e * NTOK + pos];
    const int n = entry >> 1;
    const float4 v0 = ((const float4*)(x + (size_t)n * DDIM))[lane * 2];
    const float4 v1 = ((const float4*)(x + (size_t)n * DDIM))[lane * 2 + 1];
    bf16x8 bv;
    bv[0] = (bf16)v0.x; bv[1] = (bf16)v0.y; bv[2] = (bf16)v0.z; bv[3] = (bf16)v0.w;
    bv[4] = (bf16)v1.x; bv[5] = (bf16)v1.y; bv[6] = (bf16)v1.z; bv[7] = (bf16)v1.w;
    *(bf16x8*)(xg + (size_t)slot * DDIM + lane * 8) = bv;
}

// ---------------------------------------------------------------------------
template <int R, int C>
__global__ __launch_bounds__(256)
void transpose_cvt(const float* __restrict__ in, bf16* __restrict__ outp) {
    __shared__ float tile[32][33];
    const int e = blockIdx.z;
    const int x0 = blockIdx.x * 32;
    const int y0 = blockIdx.y * 32;
    const int tx = threadIdx.x & 31, ty = threadIdx.x >> 5;
    const float* ip = in + (size_t)e * R * C;
    bf16* op = outp + (size_t)e * R * C;
#pragma unroll
    for (int q = 0; q < 4; ++q)
        tile[ty + q * 8][tx] = ip[(size_t)(y0 + ty + q * 8) * C + x0 + tx];
    __syncthreads();
#pragma unroll
    for (int q = 0; q < 4; ++q)
        op[(size_t)(x0 + ty + q * 8) * R + y0 + tx] = (bf16)tile[tx][ty + q * 8];
}

// ---------------------------------------------------------------------------
// ffn_mfma with DIAGNOSTIC VARIANTS (template VAR):
//  VAR 0: real — GL2LDS staging, XOR-permuted source chunks, XOR ds_read.
//  VAR 1: NOSTAGE — no global staging at all; LDS zero-filled once.
//         Isolates compute+barrier floor.
//  VAR 3: LINEAR — GL2LDS with linear (non-permuted) source chunks and linear
//         ds_read (correct math; accepts LDS read bank conflicts).
//         Tests "permuted per-lane source fragments coalescing".
//  VAR 4: REGSTAGE — per-lane global_load -> VGPR -> swizzled ds_write_b128
//         (same final LDS layout as VAR 0). Tests "GL2LDS instr is the binder".
// ---------------------------------------------------------------------------
template <int KD, int ND, bool PASS2, int VAR>
__global__ __launch_bounds__(256)
void ffn_mfma(const bf16* __restrict__ A_src, const bf16* __restrict__ Wt,
              const float* __restrict__ bias, const int* __restrict__ counts,
              const int* __restrict__ cumoff, const int* __restrict__ rb_e,
              const int* __restrict__ rb_r, const unsigned short* __restrict__ list,
              const float* __restrict__ gates,
              float* __restrict__ y_out, bf16* __restrict__ h_out) {
    const int e = rb_e[blockIdx.y];
    if (e < 0) return;
    const int row0 = rb_r[blockIdx.y];
    const int cnt = counts[e * 64];
    const int slotbase = cumoff[e] + row0;
    const int col0 = blockIdx.x * 128;

    __shared__ __align__(16) short As[2][128 * 64];
    __shared__ __align__(16) short Bs[2][128 * 64];

    const int t = threadIdx.x;
    const int lane = t & 63;
    const int w = t >> 6;

    if (VAR == 1) {
        // zero-fill LDS once so reads are defined; then no staging ever.
        for (int i = t; i < 2 * 128 * 64 / 8; i += 256) {
            ((bf16x8*)As)[i] = (bf16x8){0,0,0,0,0,0,0,0};
            ((bf16x8*)Bs)[i] = (bf16x8){0,0,0,0,0,0,0,0};
        }
    }

    const int subrow = lane >> 3;
    const int chunk = lane & 7;
    // VAR 0: XOR-permuted source chunk (linear LDS dest = swizzled layout)
    // VAR 3: linear source chunk (linear layout), VAR 4: linear load, swizzled ds_write
    const int swzoff = (VAR == 0) ? ((chunk ^ subrow) * 16) : (chunk * 16);
    const char* Ab = (const char*)A_src;
    const char* Bb = (const char*)Wt;
    size_t a_row_byte[4], b_row_byte[4];
#pragma unroll
    for (int q = 0; q < 4; ++q) {
        const int r = q * 32 + w * 8 + subrow;
        const int slot = slotbase + r;
        const int sclamp = slot < TOTSLOT ? slot : TOTSLOT - 1;
        a_row_byte[q] = (size_t)sclamp * KD * 2;
        b_row_byte[q] = ((size_t)e * ND + col0 + r) * KD * 2;
    }
    const int lds_wbase = w * 8 * 128;

    f32x4 acc[4][4];
#pragma unroll
    for (int i = 0; i < 4; ++i)
#pragma unroll
        for (int j = 0; j < 4; ++j) acc[i][j] = (f32x4){0.f, 0.f, 0.f, 0.f};

    const int rowblk = (w >> 1) * 64;
    const int colblk = (w & 1) * 64;
    const int fr = lane & 15;
    const int kg = lane >> 4;

    auto STAGE = [&](int buf, int k0) {
        if (VAR == 1) return;
        const size_t koff = (size_t)k0 * 2 + swzoff;
        if (VAR == 4) {
            // reg-staging: linear 16B load, swizzled ds_write (same layout as VAR0)
            const int dsw = ((chunk ^ subrow) * 16) + subrow * 128;
#pragma unroll
            for (int q = 0; q < 4; ++q) {
                const bf16x8 va = *(const bf16x8*)(Ab + a_row_byte[q] + koff);
                const bf16x8 vb = *(const bf16x8*)(Bb + b_row_byte[q] + koff);
                *(bf16x8*)((char*)As + buf * 16384 + lds_wbase + q * 4096 + dsw) = va;
                *(bf16x8*)((char*)Bs + buf * 16384 + lds_wbase + q * 4096 + dsw) = vb;
            }
        } else {
            char* ab = (char*)As + buf * 16384 + lds_wbase;
            char* bb = (char*)Bs + buf * 16384 + lds_wbase;
#pragma unroll
            for (int q = 0; q < 4; ++q) {
                GL2LDS(Ab + a_row_byte[q] + koff, ab + q * 4096);
                GL2LDS(Bb + b_row_byte[q] + koff, bb + q * 4096);
            }
        }
    };

    auto COMPUTE = [&](int buf) {
        const char* AsB = (const char*)As + buf * 16384;
        const char* BsB = (const char*)Bs + buf * 16384;
#pragma unroll
        for (int kk = 0; kk < 2; ++kk) {
            bf16x8 af[4], bg[4];
#pragma unroll
            for (int i = 0; i < 4; ++i) {
                const int ra = rowblk + i * 16 + fr;
                const int ca = (VAR == 3) ? (kk * 4 + kg) : ((kk * 4 + kg) ^ (ra & 7));
                af[i] = *(const bf16x8*)(AsB + ra * 128 + ca * 16);
                const int rb = colblk + i * 16 + fr;
                const int cb = (VAR == 3) ? (kk * 4 + kg) : ((kk * 4 + kg) ^ (rb & 7));
                bg[i] = *(const bf16x8*)(BsB + rb * 128 + cb * 16);
            }
#pragma unroll
            for (int i = 0; i < 4; ++i)
#pragma unroll
                for (int j = 0; j < 4; ++j)
                    acc[i][j] = __builtin_amdgcn_mfma_f32_16x16x32_bf16(
                        af[i], bg[j], acc[i][j], 0, 0, 0);
        }
    };

    constexpr int NT = KD / 64;
    STAGE(0, 0);
    __syncthreads();
    for (int kt = 0; kt < NT - 1; ++kt) {
        STAGE((kt + 1) & 1, (kt + 1) * 64);
        COMPUTE(kt & 1);
        __syncthreads();
    }
    COMPUTE((NT - 1) & 1);

    float bcol[4];
#pragma unroll
    for (int j = 0; j < 4; ++j)
        bcol[j] = bias[e * ND + col0 + colblk + j * 16 + fr];

#pragma unroll
    for (int i = 0; i < 4; ++i) {
#pragma unroll
        for (int rg = 0; rg < 4; ++rg) {
            const int r = rowblk + i * 16 + kg * 4 + rg;
            if (row0 + r >= cnt) continue;
            if (!PASS2) {
                bf16* hr = h_out + (size_t)(slotbase + r) * HDIM + col0 + colblk + fr;
#pragma unroll
                for (int j = 0; j < 4; ++j)
                    hr[j * 16] = (bf16)fmaxf(acc[i][j][rg] + bcol[j], 0.f);
            } else {
                const int entry = list[e * NTOK + row0 + r];
                const float g = gates[entry];
                float* yr = y_out + (size_t)(entry >> 1) * DDIM + col0 + colblk + fr;
#pragma unroll
                for (int j = 0; j < 4; ++j)
                    atomicAdd(&yr[j * 16], g * (acc[i][j][rg] + bcol[j]));
            }
        }
    }
}

// ---------------------------------------------------------------------------
__global__ __launch_bounds__(256)
void finalize_kernel(const int* __restrict__ counts,
                     const float* __restrict__ psum_part,
                     const float* __restrict__ zl_part,
                     float* __restrict__ outp) {
    __shared__ float sp[NEXP];
    __shared__ float sz;
    const int t = threadIdx.x;
    if (t < NEXP) sp[t] = 0.f;
    if (t == 0) sz = 0.f;
    __syncthreads();
    float pe[NEXP] = {0.f, 0.f, 0.f, 0.f, 0.f, 0.f, 0.f, 0.f};
    float z = 0.f;
    for (int b = t; b < NBLK_GATE; b += 256) {
#pragma unroll
        for (int e = 0; e < NEXP; ++e) pe[e] += psum_part[b * NEXP + e];
        z += zl_part[b];
    }
#pragma unroll
    for (int e = 0; e < NEXP; ++e) atomicAdd(&sp[e], pe[e]);
    atomicAdd(&sz, z);
    __syncthreads();
    if (t == 0) {
        float S = 0.f;
        for (int e = 0; e < NEXP; ++e) S += sp[e];
        const float F = (float)(NTOK * TOPK);
        float sw = 0.f;
        for (int e = 0; e < NEXP; ++e)
            sw += (sp[e] / S) * ((float)counts[e * 64] / F);
        sw *= (float)NEXP;
        const float zl = sz / (float)NTOK;
        outp[(size_t)NTOK * DDIM] = 0.01f * sw + 0.001f * zl;
    }
}

extern "C" void kernel_launch(void* const* d_in, const int* in_sizes, int n_in,
                              void* d_out, int out_size, void* d_ws, size_t ws_size,
                              hipStream_t stream) {
    (void)in_sizes; (void)n_in; (void)out_size; (void)ws_size;
    const float* x  = (const float*)d_in[0];
    const float* wg = (const float*)d_in[1];
    const float* w1 = (const float*)d_in[2];
    const float* b1 = (const float*)d_in[3];
    const float* w2 = (const float*)d_in[4];
    const float* b2 = (const float*)d_in[5];
    float* y = (float*)d_out;

    char* ws = (char*)d_ws;
    int*   counts    = (int*)(ws + 0);
    int*   cumoff    = (int*)(ws + WS_CUMOFF_OFF);
    int*   rb_e      = (int*)(ws + WS_RBE_OFF);
    int*   rb_r      = (int*)(ws + WS_RBR_OFF);
    float* psum_part = (float*)(ws + WS_PSUM_PART_OFF);
    float* zl_part   = (float*)(ws + WS_ZL_PART_OFF);
    float* gates     = (float*)(ws + WS_GATES_OFF);
    unsigned short* list = (unsigned short*)(ws + WS_LIST_OFF);
    bf16*  xg        = (bf16*)(ws + WS_XG_OFF);
    bf16*  w1t       = (bf16*)(ws + WS_W1T_OFF);
    bf16*  w2t       = (bf16*)(ws + WS_W2T_OFF);
    bf16*  hb        = (bf16*)(ws + WS_HB_OFF);

    hipMemsetAsync(ws, 0, 4096, stream);
    hipMemsetAsync(d_out, 0, (size_t)NTOK * DDIM * sizeof(float), stream);

    transpose_cvt<DDIM, HDIM><<<dim3(HDIM / 32, DDIM / 32, NEXP), 256, 0, stream>>>(w1, w1t);
    transpose_cvt<HDIM, DDIM><<<dim3(DDIM / 32, HDIM / 32, NEXP), 256, 0, stream>>>(w2, w2t);

    gate_kernel<<<NBLK_GATE, 256, 0, stream>>>(x, wg, counts, psum_part, zl_part,
                                               gates, list);
    plan_kernel<<<1, 64, 0, stream>>>(counts, cumoff, rb_e, rb_r);
    pack_kernel<<<TOTSLOT / 4, 256, 0, stream>>>(x, list, cumoff, xg);

    // ---- DIAGNOSTIC VARIANTS (pass-1 shape; outputs overwritten by real pass1) ----
    ffn_mfma<DDIM, HDIM, false, 1>   // NOSTAGE: compute+barrier floor
        <<<dim3(HDIM / 128, RBMAX), 256, 0, stream>>>(
            xg, w1t, b1, counts, cumoff, rb_e, rb_r, list, gates, nullptr, hb);
    ffn_mfma<DDIM, HDIM, false, 3>   // LINEAR source + linear reads
        <<<dim3(HDIM / 128, RBMAX), 256, 0, stream>>>(
            xg, w1t, b1, counts, cumoff, rb_e, rb_r, list, gates, nullptr, hb);
    ffn_mfma<DDIM, HDIM, false, 4>   // REG-STAGE (load->VGPR->swizzled ds_write)
        <<<dim3(HDIM / 128, RBMAX), 256, 0, stream>>>(
            xg, w1t, b1, counts, cumoff, rb_e, rb_r, list, gates, nullptr, hb);

    // ---- REAL pipeline (unchanged) ----
    ffn_mfma<DDIM, HDIM, false, 0>
        <<<dim3(HDIM / 128, RBMAX), 256, 0, stream>>>(
            xg, w1t, b1, counts, cumoff, rb_e, rb_r, list, gates, nullptr, hb);

    ffn_mfma<HDIM, DDIM, true, 0>
        <<<dim3(DDIM / 128, RBMAX), 256, 0, stream>>>(
            hb, w2t, b2, counts, cumoff, rb_e, rb_r, list, gates, y, nullptr);

    finalize_kernel<<<1, 256, 0, stream>>>(counts, psum_part, zl_part, y);
}

// Round 10
// 277.182 us; speedup vs baseline: 1.3968x; 1.3968x over previous
//
#include <hip/hip_runtime.h>
#include <hip/hip_bf16.h>
#include <math.h>

// Problem constants (B=4, L=2048 -> N=8192 tokens)
#define NTOK 8192
#define DDIM 512
#define HDIM 1024
#define NEXP 8
#define TOPK 2
#define TOTSLOT (NTOK * TOPK)    // 16384 token-expert slots
#define NBLK_GATE (NTOK / 4)     // 2048 gate blocks (4 tokens each)
#define RBMAX 144                // >= max Sum_e ceil(cnt_e/128) = 135

typedef __bf16 bf16;
typedef __attribute__((ext_vector_type(8))) __bf16 bf16x8;
typedef __attribute__((ext_vector_type(4))) float f32x4;

// ---------------- workspace layout (bytes), total 67,383,296 ----------------
#define WS_CUMOFF_OFF     2048                    // int[9]
#define WS_RBE_OFF        2112                    // int[144]
#define WS_RBR_OFF        2688                    // int[144]
#define WS_PSUM_PART_OFF  4096                    // [2048][8] f32
#define WS_ZL_PART_OFF    69632                   // [2048] f32
#define WS_GATES_OFF      77824                   // [16384] f32
#define WS_LIST_OFF       143360                  // ushort[8][8192]
#define WS_XG_OFF         274432                  // bf16[16384][512]
#define WS_W1T_OFF        17051648                // bf16[E][H][D]
#define WS_W2T_OFF        25440256                // bf16[E][D][H]
#define WS_HB_OFF         33828864                // bf16[16384][1024]

// ---------------------------------------------------------------------------
// Gating (unchanged, passing).
// ---------------------------------------------------------------------------
__global__ __launch_bounds__(256)
void gate_kernel(const float* __restrict__ x, const float* __restrict__ wg,
                 int* __restrict__ counts, float* __restrict__ psum_part,
                 float* __restrict__ zl_part, float* __restrict__ gates,
                 unsigned short* __restrict__ list) {
    __shared__ float wls[NEXP * DDIM];
    __shared__ float blk_psum[NEXP];
    __shared__ float blk_zl;
    const int t = threadIdx.x;

    for (int i = t; i < NEXP * DDIM / 4; i += 256)
        ((float4*)wls)[i] = ((const float4*)wg)[i];
    if (t < NEXP) blk_psum[t] = 0.f;
    if (t == 0) blk_zl = 0.f;
    __syncthreads();

    const int wave = t >> 6, lane = t & 63;
    const int n = blockIdx.x * 4 + wave;
    const float* xr = x + (size_t)n * DDIM;

    float acc[NEXP];
#pragma unroll
    for (int e = 0; e < NEXP; ++e) acc[e] = 0.f;
#pragma unroll
    for (int it = 0; it < DDIM / 64; ++it) {
        const float xv = xr[lane + 64 * it];
#pragma unroll
        for (int e = 0; e < NEXP; ++e)
            acc[e] = fmaf(xv, wls[e * DDIM + lane + 64 * it], acc[e]);
    }
#pragma unroll
    for (int e = 0; e < NEXP; ++e) {
#pragma unroll
        for (int off = 32; off > 0; off >>= 1)
            acc[e] += __shfl_xor(acc[e], off);
    }

    float m = acc[0];
#pragma unroll
    for (int e = 1; e < NEXP; ++e) m = fmaxf(m, acc[e]);
    float p[NEXP];
    float se = 0.f;
#pragma unroll
    for (int e = 0; e < NEXP; ++e) { p[e] = expf(acc[e] - m); se += p[e]; }
    const float lse = m + logf(se);
    const float inv = 1.f / se;
#pragma unroll
    for (int e = 0; e < NEXP; ++e) p[e] *= inv;

    int e0 = 0; float g0 = p[0];
#pragma unroll
    for (int e = 1; e < NEXP; ++e) if (p[e] > g0) { g0 = p[e]; e0 = e; }
    int e1 = -1; float g1 = -1.f;
#pragma unroll
    for (int e = 0; e < NEXP; ++e) if (e != e0 && p[e] > g1) { g1 = p[e]; e1 = e; }
    const float denom = g0 + g1 + 1e-6f;

    if (lane == 0) {
        gates[n * 2 + 0] = g0 / denom;
        gates[n * 2 + 1] = g1 / denom;
        const int p0 = atomicAdd(&counts[e0 * 64], 1);
        list[e0 * NTOK + p0] = (unsigned short)(n * 2 + 0);
        const int p1 = atomicAdd(&counts[e1 * 64], 1);
        list[e1 * NTOK + p1] = (unsigned short)(n * 2 + 1);
#pragma unroll
        for (int e = 0; e < NEXP; ++e) atomicAdd(&blk_psum[e], p[e]);
        atomicAdd(&blk_zl, lse * lse);
    }
    __syncthreads();
    if (t < NEXP) psum_part[blockIdx.x * NEXP + t] = blk_psum[t];
    if (t == 0) zl_part[blockIdx.x] = blk_zl;
}

// ---------------------------------------------------------------------------
__global__ void plan_kernel(const int* __restrict__ counts, int* __restrict__ cumoff,
                            int* __restrict__ rb_e, int* __restrict__ rb_r) {
    if (threadIdx.x == 0 && blockIdx.x == 0) {
        int off = 0, idx = 0;
        for (int e = 0; e < NEXP; ++e) {
            cumoff[e] = off;
            const int c = counts[e * 64];
            off += c;
            for (int r = 0; r < c; r += 128) { rb_e[idx] = e; rb_r[idx] = r; ++idx; }
        }
        cumoff[NEXP] = off;
        for (; idx < RBMAX; ++idx) { rb_e[idx] = -1; rb_r[idx] = 0; }
    }
}

// ---------------------------------------------------------------------------
__global__ __launch_bounds__(256)
void pack_kernel(const float* __restrict__ x, const unsigned short* __restrict__ list,
                 const int* __restrict__ cumoff, bf16* __restrict__ xg) {
    const int wave = threadIdx.x >> 6, lane = threadIdx.x & 63;
    const int slot = blockIdx.x * 4 + wave;
    int e = 0;
#pragma unroll
    for (int k = 1; k < NEXP; ++k) e += (slot >= cumoff[k]) ? 1 : 0;
    const int pos = slot - cumoff[e];
    const int entry = list[e * NTOK + pos];
    const int n = entry >> 1;
    const float4 v0 = ((const float4*)(x + (size_t)n * DDIM))[lane * 2];
    const float4 v1 = ((const float4*)(x + (size_t)n * DDIM))[lane * 2 + 1];
    bf16x8 bv;
    bv[0] = (bf16)v0.x; bv[1] = (bf16)v0.y; bv[2] = (bf16)v0.z; bv[3] = (bf16)v0.w;
    bv[4] = (bf16)v1.x; bv[5] = (bf16)v1.y; bv[6] = (bf16)v1.z; bv[7] = (bf16)v1.w;
    *(bf16x8*)(xg + (size_t)slot * DDIM + lane * 8) = bv;
}

// ---------------------------------------------------------------------------
template <int R, int C>
__global__ __launch_bounds__(256)
void transpose_cvt(const float* __restrict__ in, bf16* __restrict__ outp) {
    __shared__ float tile[32][33];
    const int e = blockIdx.z;
    const int x0 = blockIdx.x * 32;
    const int y0 = blockIdx.y * 32;
    const int tx = threadIdx.x & 31, ty = threadIdx.x >> 5;
    const float* ip = in + (size_t)e * R * C;
    bf16* op = outp + (size_t)e * R * C;
#pragma unroll
    for (int q = 0; q < 4; ++q)
        tile[ty + q * 8][tx] = ip[(size_t)(y0 + ty + q * 8) * C + x0 + tx];
    __syncthreads();
#pragma unroll
    for (int q = 0; q < 4; ++q)
        op[(size_t)(x0 + ty + q * 8) * R + y0 + tx] = (bf16)tile[tx][ty + q * 8];
}

// ---------------------------------------------------------------------------
// Dense expert-packed bf16 MFMA GEMM, 128x128 tile, BK=64, 4 waves.
// REG-STAGING (round-8 ablation): linear coalesced per-lane 16B global loads
// -> VGPR -> swizzled ds_write_b128 giving LDS[r][p] = global chunk p^(r&7);
// XOR ds_read -> conflict-free. T14 split: LOAD(next) before COMPUTE(cur),
// WRITE(next) after; one barrier per K-step.
// ROUND-9 BUGFIX: LOAD takes a TILE INDEX; byte offset is kt0*128 (64 elem
// * 2 B), not kt0*2 — the round-9 failure was this units error.
// PASS2=false: h[slot] = relu(xg[slot] @ w1t[e]^T + b1[e])     KD=512  ND=1024
// PASS2=true : y[n]   += gate * (hb[slot] @ w2t[e]^T + b2[e])  KD=1024 ND=512
// ---------------------------------------------------------------------------
template <int KD, int ND, bool PASS2>
__global__ __launch_bounds__(256)
void ffn_mfma(const bf16* __restrict__ A_src, const bf16* __restrict__ Wt,
              const float* __restrict__ bias, const int* __restrict__ counts,
              const int* __restrict__ cumoff, const int* __restrict__ rb_e,
              const int* __restrict__ rb_r, const unsigned short* __restrict__ list,
              const float* __restrict__ gates,
              float* __restrict__ y_out, bf16* __restrict__ h_out) {
    const int e = rb_e[blockIdx.y];
    if (e < 0) return;
    const int row0 = rb_r[blockIdx.y];
    const int cnt = counts[e * 64];
    const int slotbase = cumoff[e] + row0;
    const int col0 = blockIdx.x * 128;

    __shared__ __align__(16) short As[2][128 * 64];
    __shared__ __align__(16) short Bs[2][128 * 64];

    const int t = threadIdx.x;
    const int lane = t & 63;
    const int w = t >> 6;

    const int subrow = lane >> 3;     // 0..7 (row within wave's 8-row slab)
    const int chunk = lane & 7;       // 0..7 (16B chunk within 128B row)
    const size_t koff_lane = (size_t)chunk * 16;     // LINEAR source chunk
    const int dsw = subrow * 128 + ((chunk ^ subrow) * 16);  // swizzled LDS dest
    const char* Ab = (const char*)A_src;
    const char* Bb = (const char*)Wt;
    size_t a_row_byte[4], b_row_byte[4];
#pragma unroll
    for (int q = 0; q < 4; ++q) {
        const int r = q * 32 + w * 8 + subrow;
        const int slot = slotbase + r;
        const int sclamp = slot < TOTSLOT ? slot : TOTSLOT - 1;
        a_row_byte[q] = (size_t)sclamp * KD * 2;
        b_row_byte[q] = ((size_t)e * ND + col0 + r) * KD * 2;
    }
    const int lds_wbase = w * 8 * 128;

    f32x4 acc[4][4];
#pragma unroll
    for (int i = 0; i < 4; ++i)
#pragma unroll
        for (int j = 0; j < 4; ++j) acc[i][j] = (f32x4){0.f, 0.f, 0.f, 0.f};

    const int rowblk = (w >> 1) * 64;
    const int colblk = (w & 1) * 64;
    const int fr = lane & 15;
    const int kg = lane >> 4;

    bf16x8 va[4], vb[4];   // in-flight staged tile (32 VGPRs)

    auto LOAD = [&](int kt0) {
        // kt0 is a TILE index: byte offset = kt0 * 64 elem * 2 B = kt0 * 128.
        const size_t koff = (size_t)kt0 * 128 + koff_lane;
#pragma unroll
        for (int q = 0; q < 4; ++q) {
            va[q] = *(const bf16x8*)(Ab + a_row_byte[q] + koff);
            vb[q] = *(const bf16x8*)(Bb + b_row_byte[q] + koff);
        }
    };
    auto WRITE = [&](int buf) {
#pragma unroll
        for (int q = 0; q < 4; ++q) {
            *(bf16x8*)((char*)As + buf * 16384 + lds_wbase + q * 4096 + dsw) = va[q];
            *(bf16x8*)((char*)Bs + buf * 16384 + lds_wbase + q * 4096 + dsw) = vb[q];
        }
    };
    auto COMPUTE = [&](int buf) {
        const char* AsB = (const char*)As + buf * 16384;
        const char* BsB = (const char*)Bs + buf * 16384;
#pragma unroll
        for (int kk = 0; kk < 2; ++kk) {
            bf16x8 af[4], bg[4];
#pragma unroll
            for (int i = 0; i < 4; ++i) {
                const int ra = rowblk + i * 16 + fr;
                const int ca = (kk * 4 + kg) ^ (ra & 7);
                af[i] = *(const bf16x8*)(AsB + ra * 128 + ca * 16);
                const int rb = colblk + i * 16 + fr;
                const int cb = (kk * 4 + kg) ^ (rb & 7);
                bg[i] = *(const bf16x8*)(BsB + rb * 128 + cb * 16);
            }
#pragma unroll
            for (int i = 0; i < 4; ++i)
#pragma unroll
                for (int j = 0; j < 4; ++j)
                    acc[i][j] = __builtin_amdgcn_mfma_f32_16x16x32_bf16(
                        af[i], bg[j], acc[i][j], 0, 0, 0);
        }
    };

    constexpr int NT = KD / 64;
    LOAD(0);
    WRITE(0);
    __syncthreads();
    for (int kt = 0; kt < NT - 1; ++kt) {
        LOAD(kt + 1);               // issue next-tile global loads (latency hidden)
        COMPUTE(kt & 1);            // MFMA on current tile
        WRITE((kt + 1) & 1);        // vmcnt drain + ds_write after compute
        __syncthreads();
    }
    COMPUTE((NT - 1) & 1);

    // --- epilogue --- C/D mapping: col = colblk + j*16 + fr, row = kg*4 + rg
    float bcol[4];
#pragma unroll
    for (int j = 0; j < 4; ++j)
        bcol[j] = bias[e * ND + col0 + colblk + j * 16 + fr];

#pragma unroll
    for (int i = 0; i < 4; ++i) {
#pragma unroll
        for (int rg = 0; rg < 4; ++rg) {
            const int r = rowblk + i * 16 + kg * 4 + rg;
            if (row0 + r >= cnt) continue;
            if (!PASS2) {
                bf16* hr = h_out + (size_t)(slotbase + r) * HDIM + col0 + colblk + fr;
#pragma unroll
                for (int j = 0; j < 4; ++j)
                    hr[j * 16] = (bf16)fmaxf(acc[i][j][rg] + bcol[j], 0.f);
            } else {
                const int entry = list[e * NTOK + row0 + r];
                const float g = gates[entry];
                float* yr = y_out + (size_t)(entry >> 1) * DDIM + col0 + colblk + fr;
#pragma unroll
                for (int j = 0; j < 4; ++j)
                    atomicAdd(&yr[j * 16], g * (acc[i][j][rg] + bcol[j]));
            }
        }
    }
}

// ---------------------------------------------------------------------------
__global__ __launch_bounds__(256)
void finalize_kernel(const int* __restrict__ counts,
                     const float* __restrict__ psum_part,
                     const float* __restrict__ zl_part,
                     float* __restrict__ outp) {
    __shared__ float sp[NEXP];
    __shared__ float sz;
    const int t = threadIdx.x;
    if (t < NEXP) sp[t] = 0.f;
    if (t == 0) sz = 0.f;
    __syncthreads();
    float pe[NEXP] = {0.f, 0.f, 0.f, 0.f, 0.f, 0.f, 0.f, 0.f};
    float z = 0.f;
    for (int b = t; b < NBLK_GATE; b += 256) {
#pragma unroll
        for (int e = 0; e < NEXP; ++e) pe[e] += psum_part[b * NEXP + e];
        z += zl_part[b];
    }
#pragma unroll
    for (int e = 0; e < NEXP; ++e) atomicAdd(&sp[e], pe[e]);
    atomicAdd(&sz, z);
    __syncthreads();
    if (t == 0) {
        float S = 0.f;
        for (int e = 0; e < NEXP; ++e) S += sp[e];
        const float F = (float)(NTOK * TOPK);
        float sw = 0.f;
        for (int e = 0; e < NEXP; ++e)
            sw += (sp[e] / S) * ((float)counts[e * 64] / F);
        sw *= (float)NEXP;
        const float zl = sz / (float)NTOK;
        outp[(size_t)NTOK * DDIM] = 0.01f * sw + 0.001f * zl;
    }
}

extern "C" void kernel_launch(void* const* d_in, const int* in_sizes, int n_in,
                              void* d_out, int out_size, void* d_ws, size_t ws_size,
                              hipStream_t stream) {
    (void)in_sizes; (void)n_in; (void)out_size; (void)ws_size;
    const float* x  = (const float*)d_in[0];
    const float* wg = (const float*)d_in[1];
    const float* w1 = (const float*)d_in[2];
    const float* b1 = (const float*)d_in[3];
    const float* w2 = (const float*)d_in[4];
    const float* b2 = (const float*)d_in[5];
    float* y = (float*)d_out;

    char* ws = (char*)d_ws;
    int*   counts    = (int*)(ws + 0);
    int*   cumoff    = (int*)(ws + WS_CUMOFF_OFF);
    int*   rb_e      = (int*)(ws + WS_RBE_OFF);
    int*   rb_r      = (int*)(ws + WS_RBR_OFF);
    float* psum_part = (float*)(ws + WS_PSUM_PART_OFF);
    float* zl_part   = (float*)(ws + WS_ZL_PART_OFF);
    float* gates     = (float*)(ws + WS_GATES_OFF);
    unsigned short* list = (unsigned short*)(ws + WS_LIST_OFF);
    bf16*  xg        = (bf16*)(ws + WS_XG_OFF);
    bf16*  w1t       = (bf16*)(ws + WS_W1T_OFF);
    bf16*  w2t       = (bf16*)(ws + WS_W2T_OFF);
    bf16*  hb        = (bf16*)(ws + WS_HB_OFF);

    hipMemsetAsync(ws, 0, 4096, stream);
    hipMemsetAsync(d_out, 0, (size_t)NTOK * DDIM * sizeof(float), stream);

    transpose_cvt<DDIM, HDIM><<<dim3(HDIM / 32, DDIM / 32, NEXP), 256, 0, stream>>>(w1, w1t);
    transpose_cvt<HDIM, DDIM><<<dim3(DDIM / 32, HDIM / 32, NEXP), 256, 0, stream>>>(w2, w2t);

    gate_kernel<<<NBLK_GATE, 256, 0, stream>>>(x, wg, counts, psum_part, zl_part,
                                               gates, list);
    plan_kernel<<<1, 64, 0, stream>>>(counts, cumoff, rb_e, rb_r);
    pack_kernel<<<TOTSLOT / 4, 256, 0, stream>>>(x, list, cumoff, xg);

    ffn_mfma<DDIM, HDIM, false>
        <<<dim3(HDIM / 128, RBMAX), 256, 0, stream>>>(
            xg, w1t, b1, counts, cumoff, rb_e, rb_r, list, gates, nullptr, hb);

    ffn_mfma<HDIM, DDIM, true>
        <<<dim3(DDIM / 128, RBMAX), 256, 0, stream>>>(
            hb, w2t, b2, counts, cumoff, rb_e, rb_r, list, gates, y, nullptr);

    finalize_kernel<<<1, 256, 0, stream>>>(counts, psum_part, zl_part, y);
}

// Round 12
// 267.133 us; speedup vs baseline: 1.4493x; 1.0376x over previous
//
#include <hip/hip_runtime.h>
#include <hip/hip_bf16.h>
#include <math.h>

// Problem constants (B=4, L=2048 -> N=8192 tokens)
#define NTOK 8192
#define DDIM 512
#define HDIM 1024
#define NEXP 8
#define TOPK 2
#define TOTSLOT (NTOK * TOPK)    // 16384 token-expert slots
#define NBLK_GATE (NTOK / 4)     // 2048 gate blocks (4 tokens each)
#define RBMAX 144                // >= max Sum_e ceil(cnt_e/128) = 135

typedef __bf16 bf16;
typedef __attribute__((ext_vector_type(8))) __bf16 bf16x8;
typedef __attribute__((ext_vector_type(4))) float f32x4;

// ---------------- workspace layout (bytes), total 67,383,296 ----------------
#define WS_CUMOFF_OFF     2048                    // int[9]
#define WS_RBE_OFF        2112                    // int[144]
#define WS_RBR_OFF        2688                    // int[144]
#define WS_PSUM_PART_OFF  4096                    // [2048][8] f32
#define WS_ZL_PART_OFF    69632                   // [2048] f32
#define WS_GATES_OFF      77824                   // [16384] f32
#define WS_LIST_OFF       143360                  // ushort[8][8192]
#define WS_XG_OFF         274432                  // bf16[16384][512]
#define WS_W1T_OFF        17051648                // bf16[E][H][D]
#define WS_W2T_OFF        25440256                // bf16[E][D][H]
#define WS_HB_OFF         33828864                // bf16[16384][1024]

// ---------------------------------------------------------------------------
// Gating (unchanged, passing).
// ---------------------------------------------------------------------------
__global__ __launch_bounds__(256)
void gate_kernel(const float* __restrict__ x, const float* __restrict__ wg,
                 int* __restrict__ counts, float* __restrict__ psum_part,
                 float* __restrict__ zl_part, float* __restrict__ gates,
                 unsigned short* __restrict__ list) {
    __shared__ float wls[NEXP * DDIM];
    __shared__ float blk_psum[NEXP];
    __shared__ float blk_zl;
    const int t = threadIdx.x;

    for (int i = t; i < NEXP * DDIM / 4; i += 256)
        ((float4*)wls)[i] = ((const float4*)wg)[i];
    if (t < NEXP) blk_psum[t] = 0.f;
    if (t == 0) blk_zl = 0.f;
    __syncthreads();

    const int wave = t >> 6, lane = t & 63;
    const int n = blockIdx.x * 4 + wave;
    const float* xr = x + (size_t)n * DDIM;

    float acc[NEXP];
#pragma unroll
    for (int e = 0; e < NEXP; ++e) acc[e] = 0.f;
#pragma unroll
    for (int it = 0; it < DDIM / 64; ++it) {
        const float xv = xr[lane + 64 * it];
#pragma unroll
        for (int e = 0; e < NEXP; ++e)
            acc[e] = fmaf(xv, wls[e * DDIM + lane + 64 * it], acc[e]);
    }
#pragma unroll
    for (int e = 0; e < NEXP; ++e) {
#pragma unroll
        for (int off = 32; off > 0; off >>= 1)
            acc[e] += __shfl_xor(acc[e], off);
    }

    float m = acc[0];
#pragma unroll
    for (int e = 1; e < NEXP; ++e) m = fmaxf(m, acc[e]);
    float p[NEXP];
    float se = 0.f;
#pragma unroll
    for (int e = 0; e < NEXP; ++e) { p[e] = expf(acc[e] - m); se += p[e]; }
    const float lse = m + logf(se);
    const float inv = 1.f / se;
#pragma unroll
    for (int e = 0; e < NEXP; ++e) p[e] *= inv;

    int e0 = 0; float g0 = p[0];
#pragma unroll
    for (int e = 1; e < NEXP; ++e) if (p[e] > g0) { g0 = p[e]; e0 = e; }
    int e1 = -1; float g1 = -1.f;
#pragma unroll
    for (int e = 0; e < NEXP; ++e) if (e != e0 && p[e] > g1) { g1 = p[e]; e1 = e; }
    const float denom = g0 + g1 + 1e-6f;

    if (lane == 0) {
        gates[n * 2 + 0] = g0 / denom;
        gates[n * 2 + 1] = g1 / denom;
        const int p0 = atomicAdd(&counts[e0 * 64], 1);
        list[e0 * NTOK + p0] = (unsigned short)(n * 2 + 0);
        const int p1 = atomicAdd(&counts[e1 * 64], 1);
        list[e1 * NTOK + p1] = (unsigned short)(n * 2 + 1);
#pragma unroll
        for (int e = 0; e < NEXP; ++e) atomicAdd(&blk_psum[e], p[e]);
        atomicAdd(&blk_zl, lse * lse);
    }
    __syncthreads();
    if (t < NEXP) psum_part[blockIdx.x * NEXP + t] = blk_psum[t];
    if (t == 0) zl_part[blockIdx.x] = blk_zl;
}

// ---------------------------------------------------------------------------
__global__ void plan_kernel(const int* __restrict__ counts, int* __restrict__ cumoff,
                            int* __restrict__ rb_e, int* __restrict__ rb_r) {
    if (threadIdx.x == 0 && blockIdx.x == 0) {
        int off = 0, idx = 0;
        for (int e = 0; e < NEXP; ++e) {
            cumoff[e] = off;
            const int c = counts[e * 64];
            off += c;
            for (int r = 0; r < c; r += 128) { rb_e[idx] = e; rb_r[idx] = r; ++idx; }
        }
        cumoff[NEXP] = off;
        for (; idx < RBMAX; ++idx) { rb_e[idx] = -1; rb_r[idx] = 0; }
    }
}

// ---------------------------------------------------------------------------
__global__ __launch_bounds__(256)
void pack_kernel(const float* __restrict__ x, const unsigned short* __restrict__ list,
                 const int* __restrict__ cumoff, bf16* __restrict__ xg) {
    const int wave = threadIdx.x >> 6, lane = threadIdx.x & 63;
    const int slot = blockIdx.x * 4 + wave;
    int e = 0;
#pragma unroll
    for (int k = 1; k < NEXP; ++k) e += (slot >= cumoff[k]) ? 1 : 0;
    const int pos = slot - cumoff[e];
    const int entry = list[e * NTOK + pos];
    const int n = entry >> 1;
    const float4 v0 = ((const float4*)(x + (size_t)n * DDIM))[lane * 2];
    const float4 v1 = ((const float4*)(x + (size_t)n * DDIM))[lane * 2 + 1];
    bf16x8 bv;
    bv[0] = (bf16)v0.x; bv[1] = (bf16)v0.y; bv[2] = (bf16)v0.z; bv[3] = (bf16)v0.w;
    bv[4] = (bf16)v1.x; bv[5] = (bf16)v1.y; bv[6] = (bf16)v1.z; bv[7] = (bf16)v1.w;
    *(bf16x8*)(xg + (size_t)slot * DDIM + lane * 8) = bv;
}

// ---------------------------------------------------------------------------
template <int R, int C>
__global__ __launch_bounds__(256)
void transpose_cvt(const float* __restrict__ in, bf16* __restrict__ outp) {
    __shared__ float tile[32][33];
    const int e = blockIdx.z;
    const int x0 = blockIdx.x * 32;
    const int y0 = blockIdx.y * 32;
    const int tx = threadIdx.x & 31, ty = threadIdx.x >> 5;
    const float* ip = in + (size_t)e * R * C;
    bf16* op = outp + (size_t)e * R * C;
#pragma unroll
    for (int q = 0; q < 4; ++q)
        tile[ty + q * 8][tx] = ip[(size_t)(y0 + ty + q * 8) * C + x0 + tx];
    __syncthreads();
#pragma unroll
    for (int q = 0; q < 4; ++q)
        op[(size_t)(x0 + ty + q * 8) * R + y0 + tx] = (bf16)tile[tx][ty + q * 8];
}

// ---------------------------------------------------------------------------
// Dense expert-packed bf16 MFMA GEMM, 128x128 tile, BK=64, 4 waves.
// DEPTH-2 COUNTED-WAIT PIPELINE (T4; round-10 post-mortem: every vmcnt(0)-
// per-K-step structure pinned at ~70us — catalog m218: drain0 == 1-phase).
// Reg-staging with TWO named register sets (A/B, rule #20): loads for tile
// kt+2 issue while ds_write consumes the set loaded a FULL iteration earlier,
// so the compiler's register-tracked waitcnt emits vmcnt(8) (older group
// only) — counted, never 0. Unroll-by-2 K-loop; LDS double buffer unchanged;
// XOR swizzle layout unchanged (passing since r2/r10).
// PASS2=false: h[slot] = relu(xg[slot] @ w1t[e]^T + b1[e])     KD=512  ND=1024
// PASS2=true : y[n]   += gate * (hb[slot] @ w2t[e]^T + b2[e])  KD=1024 ND=512
// ---------------------------------------------------------------------------
template <int KD, int ND, bool PASS2>
__global__ __launch_bounds__(256)
void ffn_mfma(const bf16* __restrict__ A_src, const bf16* __restrict__ Wt,
              const float* __restrict__ bias, const int* __restrict__ counts,
              const int* __restrict__ cumoff, const int* __restrict__ rb_e,
              const int* __restrict__ rb_r, const unsigned short* __restrict__ list,
              const float* __restrict__ gates,
              float* __restrict__ y_out, bf16* __restrict__ h_out) {
    const int e = rb_e[blockIdx.y];
    if (e < 0) return;
    const int row0 = rb_r[blockIdx.y];
    const int cnt = counts[e * 64];
    const int slotbase = cumoff[e] + row0;
    const int col0 = blockIdx.x * 128;

    __shared__ __align__(16) short As[2][128 * 64];
    __shared__ __align__(16) short Bs[2][128 * 64];

    const int t = threadIdx.x;
    const int lane = t & 63;
    const int w = t >> 6;

    const int subrow = lane >> 3;     // 0..7 (row within wave's 8-row slab)
    const int chunk = lane & 7;       // 0..7 (16B chunk within 128B row)
    const size_t koff_lane = (size_t)chunk * 16;     // LINEAR source chunk
    const int dsw = subrow * 128 + ((chunk ^ subrow) * 16);  // swizzled LDS dest
    const char* Ab = (const char*)A_src;
    const char* Bb = (const char*)Wt;
    size_t a_row_byte[4], b_row_byte[4];
#pragma unroll
    for (int q = 0; q < 4; ++q) {
        const int r = q * 32 + w * 8 + subrow;
        const int slot = slotbase + r;
        const int sclamp = slot < TOTSLOT ? slot : TOTSLOT - 1;
        a_row_byte[q] = (size_t)sclamp * KD * 2;
        b_row_byte[q] = ((size_t)e * ND + col0 + r) * KD * 2;
    }
    const int lds_wbase = w * 8 * 128;

    f32x4 acc[4][4];
#pragma unroll
    for (int i = 0; i < 4; ++i)
#pragma unroll
        for (int j = 0; j < 4; ++j) acc[i][j] = (f32x4){0.f, 0.f, 0.f, 0.f};

    const int rowblk = (w >> 1) * 64;
    const int colblk = (w & 1) * 64;
    const int fr = lane & 15;
    const int kg = lane >> 4;

    // Two named staging register sets (depth-2 pipeline). Constant indices
    // only -> stays in VGPRs (rule #20).
    bf16x8 vaA[4], vbA[4], vaB[4], vbB[4];

    auto LOADA = [&](int kt0) {
        const size_t koff = (size_t)kt0 * 128 + koff_lane;  // tile idx * 64 elem * 2B
#pragma unroll
        for (int q = 0; q < 4; ++q) {
            vaA[q] = *(const bf16x8*)(Ab + a_row_byte[q] + koff);
            vbA[q] = *(const bf16x8*)(Bb + b_row_byte[q] + koff);
        }
    };
    auto LOADB = [&](int kt0) {
        const size_t koff = (size_t)kt0 * 128 + koff_lane;
#pragma unroll
        for (int q = 0; q < 4; ++q) {
            vaB[q] = *(const bf16x8*)(Ab + a_row_byte[q] + koff);
            vbB[q] = *(const bf16x8*)(Bb + b_row_byte[q] + koff);
        }
    };
    auto WRITEA = [&](int buf) {   // consumes set A; compiler waits only A's loads
#pragma unroll
        for (int q = 0; q < 4; ++q) {
            *(bf16x8*)((char*)As + buf * 16384 + lds_wbase + q * 4096 + dsw) = vaA[q];
            *(bf16x8*)((char*)Bs + buf * 16384 + lds_wbase + q * 4096 + dsw) = vbA[q];
        }
    };
    auto WRITEB = [&](int buf) {
#pragma unroll
        for (int q = 0; q < 4; ++q) {
            *(bf16x8*)((char*)As + buf * 16384 + lds_wbase + q * 4096 + dsw) = vaB[q];
            *(bf16x8*)((char*)Bs + buf * 16384 + lds_wbase + q * 4096 + dsw) = vbB[q];
        }
    };
    auto COMPUTE = [&](int buf) {
        const char* AsB = (const char*)As + buf * 16384;
        const char* BsB = (const char*)Bs + buf * 16384;
#pragma unroll
        for (int kk = 0; kk < 2; ++kk) {
            bf16x8 af[4], bg[4];
#pragma unroll
            for (int i = 0; i < 4; ++i) {
                const int ra = rowblk + i * 16 + fr;
                const int ca = (kk * 4 + kg) ^ (ra & 7);
                af[i] = *(const bf16x8*)(AsB + ra * 128 + ca * 16);
                const int rb = colblk + i * 16 + fr;
                const int cb = (kk * 4 + kg) ^ (rb & 7);
                bg[i] = *(const bf16x8*)(BsB + rb * 128 + cb * 16);
            }
#pragma unroll
            for (int i = 0; i < 4; ++i)
#pragma unroll
                for (int j = 0; j < 4; ++j)
                    acc[i][j] = __builtin_amdgcn_mfma_f32_16x16x32_bf16(
                        af[i], bg[j], acc[i][j], 0, 0, 0);
        }
    };

    // tiles: even tiles -> buf0, odd tiles -> buf1. NT is even (8 or 16).
    constexpr int NT = KD / 64;
    LOADA(0);                    // set A <- tile 0
    LOADB(1);                    // set B <- tile 1 (stays in flight)
    WRITEA(0);                   // waits A's 8 loads (vmcnt(8)); tile0 -> buf0
    __syncthreads();
    for (int kt = 0; kt < NT; kt += 2) {
        // half A: compute tile kt (buf0); stage tile kt+1 from set B
        if (kt + 2 < NT) LOADA(kt + 2);   // issue-early: reuse set A
        COMPUTE(0);                        // MFMA on buf0 (independent of loads)
        WRITEB(1);                         // counted wait on B's loads (1 iter old)
        __syncthreads();                   // buf1 ready; lgkm drained
        // half B: compute tile kt+1 (buf1); stage tile kt+2 from set A
        if (kt + 3 < NT) LOADB(kt + 3);
        COMPUTE(1);
        if (kt + 2 < NT) WRITEA(0);        // tile kt+2 -> buf0
        __syncthreads();
    }

    // --- epilogue --- C/D mapping: col = colblk + j*16 + fr, row = kg*4 + rg
    float bcol[4];
#pragma unroll
    for (int j = 0; j < 4; ++j)
        bcol[j] = bias[e * ND + col0 + colblk + j * 16 + fr];

#pragma unroll
    for (int i = 0; i < 4; ++i) {
#pragma unroll
        for (int rg = 0; rg < 4; ++rg) {
            const int r = rowblk + i * 16 + kg * 4 + rg;
            if (row0 + r >= cnt) continue;
            if (!PASS2) {
                bf16* hr = h_out + (size_t)(slotbase + r) * HDIM + col0 + colblk + fr;
#pragma unroll
                for (int j = 0; j < 4; ++j)
                    hr[j * 16] = (bf16)fmaxf(acc[i][j][rg] + bcol[j], 0.f);
            } else {
                const int entry = list[e * NTOK + row0 + r];
                const float g = gates[entry];
                float* yr = y_out + (size_t)(entry >> 1) * DDIM + col0 + colblk + fr;
#pragma unroll
                for (int j = 0; j < 4; ++j)
                    atomicAdd(&yr[j * 16], g * (acc[i][j][rg] + bcol[j]));
            }
        }
    }
}

// ---------------------------------------------------------------------------
__global__ __launch_bounds__(256)
void finalize_kernel(const int* __restrict__ counts,
                     const float* __restrict__ psum_part,
                     const float* __restrict__ zl_part,
                     float* __restrict__ outp) {
    __shared__ float sp[NEXP];
    __shared__ float sz;
    const int t = threadIdx.x;
    if (t < NEXP) sp[t] = 0.f;
    if (t == 0) sz = 0.f;
    __syncthreads();
    float pe[NEXP] = {0.f, 0.f, 0.f, 0.f, 0.f, 0.f, 0.f, 0.f};
    float z = 0.f;
    for (int b = t; b < NBLK_GATE; b += 256) {
#pragma unroll
        for (int e = 0; e < NEXP; ++e) pe[e] += psum_part[b * NEXP + e];
        z += zl_part[b];
    }
#pragma unroll
    for (int e = 0; e < NEXP; ++e) atomicAdd(&sp[e], pe[e]);
    atomicAdd(&sz, z);
    __syncthreads();
    if (t == 0) {
        float S = 0.f;
        for (int e = 0; e < NEXP; ++e) S += sp[e];
        const float F = (float)(NTOK * TOPK);
        float sw = 0.f;
        for (int e = 0; e < NEXP; ++e)
            sw += (sp[e] / S) * ((float)counts[e * 64] / F);
        sw *= (float)NEXP;
        const float zl = sz / (float)NTOK;
        outp[(size_t)NTOK * DDIM] = 0.01f * sw + 0.001f * zl;
    }
}

extern "C" void kernel_launch(void* const* d_in, const int* in_sizes, int n_in,
                              void* d_out, int out_size, void* d_ws, size_t ws_size,
                              hipStream_t stream) {
    (void)in_sizes; (void)n_in; (void)out_size; (void)ws_size;
    const float* x  = (const float*)d_in[0];
    const float* wg = (const float*)d_in[1];
    const float* w1 = (const float*)d_in[2];
    const float* b1 = (const float*)d_in[3];
    const float* w2 = (const float*)d_in[4];
    const float* b2 = (const float*)d_in[5];
    float* y = (float*)d_out;

    char* ws = (char*)d_ws;
    int*   counts    = (int*)(ws + 0);
    int*   cumoff    = (int*)(ws + WS_CUMOFF_OFF);
    int*   rb_e      = (int*)(ws + WS_RBE_OFF);
    int*   rb_r      = (int*)(ws + WS_RBR_OFF);
    float* psum_part = (float*)(ws + WS_PSUM_PART_OFF);
    float* zl_part   = (float*)(ws + WS_ZL_PART_OFF);
    float* gates     = (float*)(ws + WS_GATES_OFF);
    unsigned short* list = (unsigned short*)(ws + WS_LIST_OFF);
    bf16*  xg        = (bf16*)(ws + WS_XG_OFF);
    bf16*  w1t       = (bf16*)(ws + WS_W1T_OFF);
    bf16*  w2t       = (bf16*)(ws + WS_W2T_OFF);
    bf16*  hb        = (bf16*)(ws + WS_HB_OFF);

    hipMemsetAsync(ws, 0, 4096, stream);
    hipMemsetAsync(d_out, 0, (size_t)NTOK * DDIM * sizeof(float), stream);

    transpose_cvt<DDIM, HDIM><<<dim3(HDIM / 32, DDIM / 32, NEXP), 256, 0, stream>>>(w1, w1t);
    transpose_cvt<HDIM, DDIM><<<dim3(DDIM / 32, HDIM / 32, NEXP), 256, 0, stream>>>(w2, w2t);

    gate_kernel<<<NBLK_GATE, 256, 0, stream>>>(x, wg, counts, psum_part, zl_part,
                                               gates, list);
    plan_kernel<<<1, 64, 0, stream>>>(counts, cumoff, rb_e, rb_r);
    pack_kernel<<<TOTSLOT / 4, 256, 0, stream>>>(x, list, cumoff, xg);

    ffn_mfma<DDIM, HDIM, false>
        <<<dim3(HDIM / 128, RBMAX), 256, 0, stream>>>(
            xg, w1t, b1, counts, cumoff, rb_e, rb_r, list, gates, nullptr, hb);

    ffn_mfma<HDIM, DDIM, true>
        <<<dim3(DDIM / 128, RBMAX), 256, 0, stream>>>(
            hb, w2t, b2, counts, cumoff, rb_e, rb_r, list, gates, y, nullptr);

    finalize_kernel<<<1, 256, 0, stream>>>(counts, psum_part, zl_part, y);
}